// Round 13
// baseline (562.490 us; speedup 1.0000x reference)
//
#include <hip/hip_runtime.h>
#include <hip/hip_cooperative_groups.h>
#include <hip/hip_bf16.h>

namespace cg = cooperative_groups;

#define N_NODES 16384
#define N_EDGES 65536
#define NB      32
#define H       64
#define NLAYERS 3
#define NEG     0.1f
#define LN_EPS  1e-5f
#define HS_STRIDE 76   // u16; 152 B rows -> 2-way LDS banks (free)

typedef _Float16 f16;
typedef _Float16 f16x2 __attribute__((ext_vector_type(2)));
typedef _Float16 f16x8 __attribute__((ext_vector_type(8)));
typedef __fp16   hf16x2 __attribute__((ext_vector_type(2)));
typedef float    f32x16 __attribute__((ext_vector_type(16)));

union F16x8 { f16x8 v; f16x2 p[4]; int4 i4; int2 i2[2]; f16 e[8]; };
union F16x2U { f16x2 h2; hf16x2 raw; unsigned int u; };
union F16U   { f16 h; unsigned short u; };

__device__ __forceinline__ f16x2 pkrtz(float a, float b) {
    F16x2U t; t.raw = __builtin_amdgcn_cvt_pkrtz(a, b); return t.h2;
}
__device__ __forceinline__ float leaky(float v) { return v > 0.f ? v : NEG * v; }

struct Params {
    const float* x; const int* eidx; const float* ea; const int* bat;
    const float* Win; const float* bin;
    const float* ew1; const float* eb1; const float* ew2; const float* eb2;
    const float* ew3; const float* eb3;
    const float* rw;  const float* rb;  const float* lg;  const float* lb;
    const float* pw1; const float* pb1; const float* pw2; const float* pb2;
    const float* pw3; const float* pb3;
    float* out; float* ws;
};

struct MsgSmem {
    unsigned short hsL[256 * HS_STRIDE];  // 38912 B
    int dstL[256];                        // 1024 B
};                                        // 39936 B
struct NodeSmem {
    unsigned short hA[64 * 72];
    float outL[64][68];
};
struct HeadSmem {
    float cntL[32];
    float ps[32][64];
    float p1[32][64];
    float p2[32][32];
};
union __align__(16) AllSmem { MsgSmem m; NodeSmem n; HeadSmem hd; };  // 39936 B

// ---- Bp prep for one gslot (520 slots/layer; slot = i*8 + ks*2 + oq).
// i<64 slots are pi-PACKED to match the register-resident e2^T fragment layout:
//   k_hw = ks*16 + kp*8 + j  ->  kappa = 32*(ks>>1) + 16*(ks&1) + 4*kp + (j<4 ? j : 4+j)
// bias slot (i==64) keeps LINEAR k (its A-operand is h, read linearly from LDS).
__device__ __forceinline__ void bp_slot(int gslot, int lane,
                                        const float* __restrict__ ew3,
                                        const float* __restrict__ eb3,
                                        f16* __restrict__ Bp) {
    int l    = gslot / 520;
    int slot = gslot - l * 520;
    const float* ew3l = ew3 + (size_t)l * 262144;
    const float* eb3l = eb3 + (size_t)l * 4096;
    int i   = slot >> 3;
    int rem = slot & 7;
    int ks  = rem >> 1;
    int oq  = rem & 1;
    int o   = oq * 32 + (lane & 31);
    int kp  = lane >> 5;
    float v[8];
    if (i < 64) {
        int base = 32 * (ks >> 1) + 16 * (ks & 1) + 4 * kp;
        const float* s = ew3l + ((size_t)(i * 64 + o)) * 64 + base;
#pragma unroll
        for (int j = 0; j < 4; j++) v[j] = s[j];
#pragma unroll
        for (int j = 0; j < 4; j++) v[4 + j] = s[8 + j];
    } else {
        int k0 = ks * 16 + kp * 8;
#pragma unroll
        for (int j = 0; j < 8; j++) v[j] = eb3l[(k0 + j) * 64 + o];
    }
    union { int4 i4; f16 a[8]; } outw;
#pragma unroll
    for (int j = 0; j < 8; j++) outw.a[j] = (f16)v[j];
    *(int4*)(Bp + (size_t)l * 266240 + (size_t)slot * 512 + lane * 8) = outw.i4;
}

// ---- B-fragment register loads
__device__ __forceinline__ void loadB8(const f16* __restrict__ Bp, int c, int oq, int lane, F16x8* dstB) {
    const f16* base = Bp + (((size_t)(c * 16 + oq)) << 9) + lane * 8;
#pragma unroll
    for (int di = 0; di < 2; di++)
#pragma unroll
        for (int ks = 0; ks < 4; ks++)
            dstB[di * 4 + ks].i4 = *(const int4*)(base + ((di * 8 + ks * 2) << 9));
}
__device__ __forceinline__ void loadB4(const f16* __restrict__ Bp, int oq, int lane, F16x8* dstB) {
    const f16* base = Bp + (((size_t)(512 + oq)) << 9) + lane * 8;
#pragma unroll
    for (int ks = 0; ks < 4; ks++)
        dstB[ks].i4 = *(const int4*)(base + ((ks * 2) << 9));
}

// one chunk (2 i-slots): 32 MFMA across 4 tile-chains (R7 shape)
__device__ __forceinline__ void msg_chunk4(int c, const F16x8* __restrict__ B,
                                           const unsigned short* const* hp,
                                           const f16x2 (*e2p)[4][4], f32x16* C) {
    unsigned int rr[4];
#pragma unroll
    for (int tt = 0; tt < 4; tt++) rr[tt] = *(const unsigned int*)(hp[tt] + 2 * c);
#pragma unroll
    for (int di = 0; di < 2; di++) {
        unsigned int sel = di ? 0x03020302u : 0x01000100u;
        F16x2U hh[4];
#pragma unroll
        for (int tt = 0; tt < 4; tt++) hh[tt].u = __builtin_amdgcn_perm(rr[tt], rr[tt], sel);
#pragma unroll
        for (int ks = 0; ks < 4; ks++) {
#pragma unroll
            for (int tt = 0; tt < 4; tt++) {
                F16x8 A;
#pragma unroll
                for (int r = 0; r < 4; r++) A.p[r] = hh[tt].h2 * e2p[tt][ks][r];
                C[tt] = __builtin_amdgcn_mfma_f32_32x32x16_f16(A.v, B[di * 4 + ks].v, C[tt], 0, 0, 0);
            }
        }
    }
}

// ================================================================ msg body: 256 edges, 4 waves,
// wave (eh,oq) = 4 edge-tiles x 32 outputs. Edge-MLP fully in registers:
// stage-1 e1 -> B-fragments; stage-2 computes e2^T = w2 @ e1 so each lane gets
// its OWN edge's e2 straight in registers (no LDS exchange, no extra barrier).
__device__ __forceinline__ void msg_body(MsgSmem& S, const float* __restrict__ h,
        const float* __restrict__ ea,
        const float* __restrict__ w1, const float* __restrict__ b1,
        const float* __restrict__ w2, const float* __restrict__ b2,
        const f16* __restrict__ Bpl,
        const int* __restrict__ srcp, const int* __restrict__ dstp,
        float* __restrict__ agg_l, int eb, int t) {
    const int lane = t & 63;
    const int w    = t >> 6;
    const int eh   = w >> 1, oq = w & 1;
    const int m    = lane & 31;
    const int kp   = lane >> 5;

    // ---- stage all 256 h rows (gathered by src, fp32 -> f16); dst
    {
        int nsrc = srcp[eb + t];
        const float4* hr = (const float4*)(h + (size_t)nsrc * 64);
        unsigned int* hrow = (unsigned int*)S.hsL + t * (HS_STRIDE / 2);
#pragma unroll
        for (int q = 0; q < 16; q++) {
            float4 v = hr[q];
            F16x2U p0, p1;
            p0.raw = __builtin_amdgcn_cvt_pkrtz(v.x, v.y);
            p1.raw = __builtin_amdgcn_cvt_pkrtz(v.z, v.w);
            hrow[q * 2 + 0] = p0.u;
            hrow[q * 2 + 1] = p1.u;
        }
        S.dstL[t] = dstp[eb + t];
    }

    // ---- stage-2 A-operand: w2 fragments (M = output-half H, K = hidden kk)
    F16x8 W2f[2][4];
#pragma unroll
    for (int Hh = 0; Hh < 2; Hh++)
#pragma unroll
        for (int ks = 0; ks < 4; ks++) {
            const float* s = w2 + (size_t)(Hh * 32 + m) * 64 + ks * 16 + kp * 8;
            float4 a = ((const float4*)s)[0];
            float4 b = ((const float4*)s)[1];
            W2f[Hh][ks].p[0] = pkrtz(a.x, a.y);
            W2f[Hh][ks].p[1] = pkrtz(a.z, a.w);
            W2f[Hh][ks].p[2] = pkrtz(b.x, b.y);
            W2f[Hh][ks].p[3] = pkrtz(b.z, b.w);
        }
    // b2 values for this lane's C-layout rows
    float b2v[2][16];
#pragma unroll
    for (int Hh = 0; Hh < 2; Hh++)
#pragma unroll
        for (int reg = 0; reg < 16; reg++)
            b2v[Hh][reg] = b2[32 * Hh + (reg & 3) + 8 * (reg >> 2) + 4 * kp];

    // ---- stage 1: e1 B-fragments for this wave's 4 edges (one per tile)
    F16x8 A1[4][4];   // [tt][ks]; lane (m,kp): e1[kk = ks*16+kp*8+j][edge tt*32+m]
    {
        float ar[4][5];
#pragma unroll
        for (int tt = 0; tt < 4; tt++) {
            int edge = eb + (eh * 4 + tt) * 32 + m;
#pragma unroll
            for (int d = 0; d < 5; d++) ar[tt][d] = ea[(size_t)edge * 5 + d];
        }
#pragma unroll
        for (int ks = 0; ks < 4; ks++)
#pragma unroll
            for (int jj = 0; jj < 4; jj++) {
                int k0 = ks * 16 + kp * 8 + jj * 2;
                const float* wr0 = w1 + (size_t)k0 * 5;
                const float* wr1 = wr0 + 5;
                float bb0 = b1[k0], bb1 = b1[k0 + 1];
#pragma unroll
                for (int tt = 0; tt < 4; tt++) {
                    float v0 = bb0 + ar[tt][0] * wr0[0] + ar[tt][1] * wr0[1] + ar[tt][2] * wr0[2]
                                   + ar[tt][3] * wr0[3] + ar[tt][4] * wr0[4];
                    float v1 = bb1 + ar[tt][0] * wr1[0] + ar[tt][1] * wr1[1] + ar[tt][2] * wr1[2]
                                   + ar[tt][3] * wr1[3] + ar[tt][4] * wr1[4];
                    A1[tt][ks].p[jj] = pkrtz(leaky(v0), leaky(v1));
                }
            }
    }

    // ---- stage 2: e2^T per tile; repack C-regs into pi-ordered A-fragments
    f16x2 e2p[4][4][4];
#pragma unroll
    for (int tt = 0; tt < 4; tt++) {
        f32x16 C2[2];
#pragma unroll
        for (int r = 0; r < 16; r++) { C2[0][r] = 0.f; C2[1][r] = 0.f; }
#pragma unroll
        for (int ks = 0; ks < 4; ks++) {
            C2[0] = __builtin_amdgcn_mfma_f32_32x32x16_f16(W2f[0][ks].v, A1[tt][ks].v, C2[0], 0, 0, 0);
            C2[1] = __builtin_amdgcn_mfma_f32_32x32x16_f16(W2f[1][ks].v, A1[tt][ks].v, C2[1], 0, 0, 0);
        }
#pragma unroll
        for (int ks = 0; ks < 4; ks++) {
            int Hh = ks >> 1, rbase = (ks & 1) * 8;
#pragma unroll
            for (int jj = 0; jj < 4; jj++) {
                float v0 = leaky(C2[Hh][rbase + 2 * jj]     + b2v[Hh][rbase + 2 * jj]);
                float v1 = leaky(C2[Hh][rbase + 2 * jj + 1] + b2v[Hh][rbase + 2 * jj + 1]);
                e2p[tt][ks][jj] = pkrtz(v0, v1);
            }
        }
    }
    __syncthreads();   // hsL/dstL visibility (single barrier in msg)

    // ---- K-loop (R7 shape): 4 chains, static register dbuf, barrier-free
    f32x16 C[4];
#pragma unroll
    for (int tt = 0; tt < 4; tt++)
#pragma unroll
        for (int r = 0; r < 16; r++) C[tt][r] = 0.f;

    const unsigned short* hp[4];
#pragma unroll
    for (int tt = 0; tt < 4; tt++)
        hp[tt] = S.hsL + ((eh * 4 + tt) * 32 + m) * HS_STRIDE;

    F16x8 B0[8], B1[8];
    loadB8(Bpl, 0, oq, lane, B0);
    loadB8(Bpl, 1, oq, lane, B1);
    for (int it = 0; it < 15; it++) {
        int c = it * 2;
        msg_chunk4(c,     B0, hp, e2p, C);  loadB8(Bpl, c + 2, oq, lane, B0);
        msg_chunk4(c + 1, B1, hp, e2p, C);  loadB8(Bpl, c + 3, oq, lane, B1);
    }
    msg_chunk4(30, B0, hp, e2p, C);
    loadB4(Bpl, oq, lane, B0);              // bias frags
    msg_chunk4(31, B1, hp, e2p, C);

    // ---- bias chunk: A = h itself (linear k), B = eb3 frags
#pragma unroll
    for (int ks = 0; ks < 4; ks++) {
        int koff = (ks * 16 + kp * 8) * 2;
#pragma unroll
        for (int tt = 0; tt < 4; tt++) {
            const char* rp = (const char*)S.hsL + (size_t)((eh * 4 + tt) * 32 + m) * (HS_STRIDE * 2) + koff;
            F16x8 A;
            A.i2[0] = *(const int2*)(rp); A.i2[1] = *(const int2*)(rp + 8);
            C[tt] = __builtin_amdgcn_mfma_f32_32x32x16_f16(A.v, B0[ks].v, C[tt], 0, 0, 0);
        }
    }

    // ---- scatter epilogue
    int o = oq * 32 + m;
#pragma unroll
    for (int tt = 0; tt < 4; tt++) {
#pragma unroll
        for (int reg = 0; reg < 16; reg++) {
            int r = (reg & 3) + 8 * (reg >> 2) + 4 * kp;
            atomicAdd(&agg_l[(size_t)S.dstL[(eh * 4 + tt) * 32 + r] * 64 + o], C[tt][reg]);
        }
    }
}

// ================================================================ node / head bodies (proven)
__device__ __forceinline__ void node_body(NodeSmem& S, float* __restrict__ h,
        const float* __restrict__ agg_l, const float* __restrict__ deg,
        const float* __restrict__ rwl, const float* __restrict__ rbl,
        const float* __restrict__ lgl, const float* __restrict__ lbl,
        const int* __restrict__ bat, float* __restrict__ pooled,
        int last, int nb, int t) {
    const int lane = t & 63, w = t >> 6;
    const int nq = w >> 1, oq = w & 1;
    const int m = lane & 31, kp = lane >> 5;

    {
        int r = t >> 2, c0 = (t & 3) * 16;
        const float4* hr = (const float4*)(h + (size_t)(nb + r) * 64 + c0);
        unsigned int* drow = (unsigned int*)S.hA + r * 36 + c0 / 2;
#pragma unroll
        for (int q = 0; q < 4; q++) {
            float4 v = hr[q];
            F16x2U p0, p1;
            p0.raw = __builtin_amdgcn_cvt_pkrtz(v.x, v.y);
            p1.raw = __builtin_amdgcn_cvt_pkrtz(v.z, v.w);
            drow[q * 2] = p0.u; drow[q * 2 + 1] = p1.u;
        }
    }
    F16x8 Bf[4];
#pragma unroll
    for (int ks = 0; ks < 4; ks++) {
        const float* s = rwl + (size_t)(oq * 32 + m) * 64 + ks * 16 + kp * 8;
        float4 a = ((const float4*)s)[0];
        float4 b = ((const float4*)s)[1];
        Bf[ks].p[0] = pkrtz(a.x, a.y);
        Bf[ks].p[1] = pkrtz(a.z, a.w);
        Bf[ks].p[2] = pkrtz(b.x, b.y);
        Bf[ks].p[3] = pkrtz(b.z, b.w);
    }
    __syncthreads();

    f32x16 C = {0,0,0,0,0,0,0,0,0,0,0,0,0,0,0,0};
#pragma unroll
    for (int ks = 0; ks < 4; ks++) {
        F16x8 A;
        A.i4 = *(const int4*)(S.hA + (size_t)(nq * 32 + m) * 72 + ks * 16 + kp * 8);
        C = __builtin_amdgcn_mfma_f32_32x32x16_f16(A.v, Bf[ks].v, C, 0, 0, 0);
    }

    int o = oq * 32 + m;
#pragma unroll
    for (int reg = 0; reg < 16; reg++) {
        int r = (reg & 3) + 8 * (reg >> 2) + 4 * kp;
        int n = nq * 32 + r;
        S.outL[n][o] = C[reg] + rbl[o] + agg_l[(size_t)(nb + n) * 64 + o] / fmaxf(deg[nb + n], 1.0f);
    }
    __syncthreads();

    float gj = lgl[lane], bj = lbl[lane];
    float accp = 0.f;
    int cur = bat[nb + w * 16];
    for (int q = 0; q < 16; q++) {
        int n = w * 16 + q;
        float v = S.outL[n][lane];
        float mu = v;
#pragma unroll
        for (int msk = 32; msk > 0; msk >>= 1) mu += __shfl_xor(mu, msk);
        mu *= (1.f / 64.f);
        float d = v - mu;
        float var = d * d;
#pragma unroll
        for (int msk = 32; msk > 0; msk >>= 1) var += __shfl_xor(var, msk);
        var *= (1.f / 64.f);
        float ov = d * rsqrtf(var + LN_EPS) * gj + bj;
        float hn = leaky(ov) + h[(size_t)(nb + n) * 64 + lane];
        h[(size_t)(nb + n) * 64 + lane] = hn;
        if (last) {
            int b = bat[nb + n];
            if (b != cur) { atomicAdd(&pooled[cur * 64 + lane], accp); accp = 0.f; cur = b; }
            accp += hn;
        }
    }
    if (last) atomicAdd(&pooled[cur * 64 + lane], accp);
}

__device__ __forceinline__ void head_body(HeadSmem& S, const float* __restrict__ pooled,
        const int* __restrict__ bat,
        const float* pw1, const float* pb1, const float* pw2, const float* pb2,
        const float* pw3, const float* pb3, float* __restrict__ out, int t) {
    if (t < 32) S.cntL[t] = 0.f;
    __syncthreads();
    {
        const int4* bp4 = (const int4*)(bat + t * 64);
        int cur = bat[t * 64];
        float c = 0.f;
        for (int q = 0; q < 16; q++) {
            int4 b4 = bp4[q];
            int bs[4] = { b4.x, b4.y, b4.z, b4.w };
#pragma unroll
            for (int e = 0; e < 4; e++) {
                if (bs[e] != cur) { atomicAdd(&S.cntL[cur], c); cur = bs[e]; c = 0.f; }
                c += 1.f;
            }
        }
        atomicAdd(&S.cntL[cur], c);
    }
    __syncthreads();
    for (int idx = t; idx < 2048; idx += 256) {
        int b = idx >> 6, j = idx & 63;
        S.ps[b][j] = pooled[idx] / fmaxf(S.cntL[b], 1.0f);
    }
    __syncthreads();
    for (int idx = t; idx < 2048; idx += 256) {
        int b = idx >> 6, j = idx & 63;
        float v = pb1[j];
#pragma unroll 8
        for (int i = 0; i < 64; i++) v += S.ps[b][i] * pw1[j * 64 + i];
        S.p1[b][j] = leaky(v);
    }
    __syncthreads();
    for (int idx = t; idx < 1024; idx += 256) {
        int b = idx >> 5, j = idx & 31;
        float v = pb2[j];
#pragma unroll 8
        for (int i = 0; i < 64; i++) v += S.p1[b][i] * pw2[j * 64 + i];
        S.p2[b][j] = leaky(v);
    }
    __syncthreads();
    if (t < 32) {
        float v = pb3[0];
#pragma unroll 8
        for (int i = 0; i < 32; i++) v += S.p2[t][i] * pw3[i];
        out[t] = v;
    }
}

// ================================================================ cooperative mega-kernel (grid 256)
__global__ __launch_bounds__(256, 1) void k_all(Params P) {
    __shared__ AllSmem smem;
    cg::grid_group grid = cg::this_grid();

    const int t   = threadIdx.x;
    const int bid = blockIdx.x;
    const int w   = t >> 6;

    float* ws     = P.ws;
    float* h      = ws;
    float* agg    = ws + 1048576;
    float* deg    = ws + 4194304;
    float* pooled = ws + 4210688;
    f16*   Bp     = (f16*)(ws + 4212800);
    const int* srcp = P.eidx;
    const int* dstp = P.eidx + N_EDGES;

    // phase S: inproj + degree + Bp prep (zeroing done by host memset)
    {
        int base = bid * 4096;
#pragma unroll
        for (int q = 0; q < 16; q++) {
            int idx = base + q * 256 + t;
            int n = idx >> 6, j = idx & 63;
            const float* xr = P.x + n * 4;
            const float* wr = P.Win + j * 4;
            float v = P.bin[j] + xr[0] * wr[0] + xr[1] * wr[1] + xr[2] * wr[2] + xr[3] * wr[3];
            h[idx] = leaky(v);
        }
        atomicAdd(&deg[dstp[bid * 256 + t]], 1.0f);
        for (int gslot = bid * 4 + w; gslot < 1560; gslot += 1024)
            bp_slot(gslot, t & 63, P.ew3, P.eb3, Bp);
    }
    grid.sync();

    for (int l = 0; l < NLAYERS; l++) {
        float* agg_l = agg + (size_t)l * 1048576;
        msg_body(smem.m, h, P.ea, P.ew1 + l * 320, P.eb1 + l * 64,
                 P.ew2 + l * 4096, P.eb2 + l * 64,
                 Bp + (size_t)l * 266240, srcp, dstp, agg_l, bid * 256, t);
        grid.sync();
        node_body(smem.n, h, agg_l, deg, P.rw + l * 4096, P.rb + l * 64,
                  P.lg + l * 64, P.lb + l * 64, P.bat, pooled,
                  (l == NLAYERS - 1) ? 1 : 0, bid * 64, t);
        grid.sync();
    }

    if (bid == 0)
        head_body(smem.hd, pooled, P.bat, P.pw1, P.pb1, P.pw2, P.pb2, P.pw3, P.pb3, P.out, t);
}

// ================================================================ fallback kernels (multi-dispatch)
__global__ __launch_bounds__(256) void k_setup(const float* __restrict__ x,
                                               const float* __restrict__ Win,
                                               const float* __restrict__ bin,
                                               const int* __restrict__ dst,
                                               const float* __restrict__ ew3,
                                               const float* __restrict__ eb3,
                                               float* __restrict__ h,
                                               float* __restrict__ deg,
                                               f16* __restrict__ Bp) {
    int bid = blockIdx.x;
    if (bid < 4096) {
        int t = bid * 256 + threadIdx.x;
        int n = t >> 6, j = t & 63;
        const float* xr = x + n * 4;
        const float* wr = Win + j * 4;
        float v = bin[j] + xr[0] * wr[0] + xr[1] * wr[1] + xr[2] * wr[2] + xr[3] * wr[3];
        h[t] = leaky(v);
    } else if (bid < 4352) {
        int e = (bid - 4096) * 256 + threadIdx.x;
        atomicAdd(&deg[dst[e]], 1.0f);
    } else {
        int tg = (bid - 4352) * 256 + threadIdx.x;
        bp_slot(tg >> 6, tg & 63, ew3, eb3, Bp);
    }
}

__global__ __launch_bounds__(256, 1) void k_msg_s(const float* __restrict__ h,
                                                  const float* __restrict__ ea,
                                                  const float* __restrict__ w1,
                                                  const float* __restrict__ b1,
                                                  const float* __restrict__ w2,
                                                  const float* __restrict__ b2,
                                                  const f16* __restrict__ Bp,
                                                  const int* __restrict__ src,
                                                  const int* __restrict__ dst,
                                                  float* __restrict__ agg) {
    __shared__ MsgSmem S;
    msg_body(S, h, ea, w1, b1, w2, b2, Bp, src, dst, agg, blockIdx.x * 256, threadIdx.x);
}

__global__ __launch_bounds__(256) void k_node_s(const float* __restrict__ agg,
                                                const float* __restrict__ deg,
                                                const float* __restrict__ rw,
                                                const float* __restrict__ rb,
                                                const float* __restrict__ lg,
                                                const float* __restrict__ lb,
                                                float* __restrict__ h,
                                                const int* __restrict__ batch,
                                                float* __restrict__ pooled,
                                                int last) {
    __shared__ NodeSmem S;
    node_body(S, h, agg, deg, rw, rb, lg, lb, batch, pooled, last, blockIdx.x * 64, threadIdx.x);
}

__global__ __launch_bounds__(256) void k_head_s(const float* __restrict__ pooled,
                                                const int* __restrict__ batch,
                                                const float* __restrict__ pw1, const float* __restrict__ pb1,
                                                const float* __restrict__ pw2, const float* __restrict__ pb2,
                                                const float* __restrict__ pw3, const float* __restrict__ pb3,
                                                float* __restrict__ out) {
    __shared__ HeadSmem S;
    head_body(S, pooled, batch, pw1, pb1, pw2, pb2, pw3, pb3, out, threadIdx.x);
}

// ----------------------------------------------------------------
extern "C" void kernel_launch(void* const* d_in, const int* in_sizes, int n_in,
                              void* d_out, int out_size, void* d_ws, size_t ws_size,
                              hipStream_t stream) {
    Params hp;
    hp.x    = (const float*)d_in[0];
    hp.eidx = (const int*)  d_in[1];
    hp.ea   = (const float*)d_in[2];
    hp.bat  = (const int*)  d_in[3];
    hp.Win  = (const float*)d_in[4];
    hp.bin  = (const float*)d_in[5];
    hp.ew1  = (const float*)d_in[6];
    hp.eb1  = (const float*)d_in[7];
    hp.ew2  = (const float*)d_in[8];
    hp.eb2  = (const float*)d_in[9];
    hp.ew3  = (const float*)d_in[10];
    hp.eb3  = (const float*)d_in[11];
    hp.rw   = (const float*)d_in[12];
    hp.rb   = (const float*)d_in[13];
    hp.lg   = (const float*)d_in[14];
    hp.lb   = (const float*)d_in[15];
    hp.pw1  = (const float*)d_in[16];
    hp.pb1  = (const float*)d_in[17];
    hp.pw2  = (const float*)d_in[18];
    hp.pb2  = (const float*)d_in[19];
    hp.pw3  = (const float*)d_in[20];
    hp.pb3  = (const float*)d_in[21];
    hp.out  = (float*)d_out;
    hp.ws   = (float*)d_ws;

    float* ws  = (float*)d_ws;
    float* agg = ws + 1048576;
    (void)hipMemsetAsync(agg, 0, (size_t)3164224 * sizeof(float), stream);

    void* args[] = { (void*)&hp };
    hipError_t err = hipLaunchCooperativeKernel(reinterpret_cast<void*>(k_all),
                                                dim3(256), dim3(256), args, 0, stream);
    if (err != hipSuccess) {
        float* h      = ws;
        float* deg    = ws + 4194304;
        float* pooled = ws + 4210688;
        f16*   Bp     = (f16*)(ws + 4212800);
        const int* srcp = (const int*)d_in[1];
        const int* dstp = srcp + N_EDGES;

        k_setup<<<4742, 256, 0, stream>>>(hp.x, hp.Win, hp.bin, dstp, hp.ew3, hp.eb3, h, deg, Bp);
        for (int l = 0; l < NLAYERS; l++) {
            float* agg_l = agg + (size_t)l * 1048576;
            k_msg_s <<<N_EDGES / 256, 256, 0, stream>>>(h, hp.ea, hp.ew1 + l * 320, hp.eb1 + l * 64,
                                                        hp.ew2 + l * 4096, hp.eb2 + l * 64,
                                                        Bp + (size_t)l * 266240, srcp, dstp, agg_l);
            k_node_s<<<N_NODES / 64, 256, 0, stream>>>(agg_l, deg, hp.rw + l * 4096, hp.rb + l * 64,
                                                       hp.lg + l * 64, hp.lb + l * 64, h,
                                                       hp.bat, pooled, l == NLAYERS - 1 ? 1 : 0);
        }
        k_head_s<<<1, 256, 0, stream>>>(pooled, hp.bat, hp.pw1, hp.pb1, hp.pw2, hp.pb2,
                                        hp.pw3, hp.pb3, (float*)d_out);
    }
}

// Round 14
// 558.828 us; speedup vs baseline: 1.0066x; 1.0066x over previous
//
#include <hip/hip_runtime.h>
#include <hip/hip_cooperative_groups.h>
#include <hip/hip_bf16.h>

namespace cg = cooperative_groups;

#define N_NODES 16384
#define N_EDGES 65536
#define NB      32
#define H       64
#define NLAYERS 3
#define NEG     0.1f
#define LN_EPS  1e-5f
#define HS_STRIDE 76   // u16; 152 B rows -> 2-way LDS banks (free)

typedef _Float16 f16;
typedef _Float16 f16x2 __attribute__((ext_vector_type(2)));
typedef _Float16 f16x8 __attribute__((ext_vector_type(8)));
typedef __fp16   hf16x2 __attribute__((ext_vector_type(2)));
typedef float    f32x16 __attribute__((ext_vector_type(16)));

union F16x8 { f16x8 v; f16x2 p[4]; int4 i4; int2 i2[2]; f16 e[8]; };
union F16x2U { f16x2 h2; hf16x2 raw; unsigned int u; };
union F16U   { f16 h; unsigned short u; };

__device__ __forceinline__ f16x2 pkrtz(float a, float b) {
    F16x2U t; t.raw = __builtin_amdgcn_cvt_pkrtz(a, b); return t.h2;
}
__device__ __forceinline__ float leaky(float v) { return v > 0.f ? v : NEG * v; }

struct Params {
    const float* x; const int* eidx; const float* ea; const int* bat;
    const float* Win; const float* bin;
    const float* ew1; const float* eb1; const float* ew2; const float* eb2;
    const float* ew3; const float* eb3;
    const float* rw;  const float* rb;  const float* lg;  const float* lb;
    const float* pw1; const float* pb1; const float* pw2; const float* pb2;
    const float* pw3; const float* pb3;
    float* out; float* ws;
};

struct MsgSmem {
    unsigned short hsL[256 * HS_STRIDE];  // 38912 B
    int dstL[256];                        // 1024 B
};
struct NodeSmem {
    unsigned short hA[64 * 72];
    float outL[64][68];
};
struct HeadSmem {
    float cntL[32];
    float ps[32][64];
    float p1[32][64];
    float p2[32][32];
};
union __align__(16) AllSmem { MsgSmem m; NodeSmem n; HeadSmem hd; };  // 39936 B

// ---- Bp prep (520 slots/layer; slot = i*8 + ks*2 + oq). i<64 pi-packed to the
// register-resident e2^T fragment order; bias slot (i==64) linear k.
__device__ __forceinline__ void bp_slot(int gslot, int lane,
                                        const float* __restrict__ ew3,
                                        const float* __restrict__ eb3,
                                        f16* __restrict__ Bp) {
    int l    = gslot / 520;
    int slot = gslot - l * 520;
    const float* ew3l = ew3 + (size_t)l * 262144;
    const float* eb3l = eb3 + (size_t)l * 4096;
    int i   = slot >> 3;
    int rem = slot & 7;
    int ks  = rem >> 1;
    int oq  = rem & 1;
    int o   = oq * 32 + (lane & 31);
    int kp  = lane >> 5;
    float v[8];
    if (i < 64) {
        int base = 32 * (ks >> 1) + 16 * (ks & 1) + 4 * kp;
        const float* s = ew3l + ((size_t)(i * 64 + o)) * 64 + base;
#pragma unroll
        for (int j = 0; j < 4; j++) v[j] = s[j];
#pragma unroll
        for (int j = 0; j < 4; j++) v[4 + j] = s[8 + j];
    } else {
        int k0 = ks * 16 + kp * 8;
#pragma unroll
        for (int j = 0; j < 8; j++) v[j] = eb3l[(k0 + j) * 64 + o];
    }
    union { int4 i4; f16 a[8]; } outw;
#pragma unroll
    for (int j = 0; j < 8; j++) outw.a[j] = (f16)v[j];
    *(int4*)(Bp + (size_t)l * 266240 + (size_t)slot * 512 + lane * 8) = outw.i4;
}

// ---- B-fragment register loads
__device__ __forceinline__ void loadB8(const f16* __restrict__ Bp, int c, int oq, int lane, F16x8* dstB) {
    const f16* base = Bp + (((size_t)(c * 16 + oq)) << 9) + lane * 8;
#pragma unroll
    for (int di = 0; di < 2; di++)
#pragma unroll
        for (int ks = 0; ks < 4; ks++)
            dstB[di * 4 + ks].i4 = *(const int4*)(base + ((di * 8 + ks * 2) << 9));
}
__device__ __forceinline__ void loadB4(const f16* __restrict__ Bp, int oq, int lane, F16x8* dstB) {
    const f16* base = Bp + (((size_t)(512 + oq)) << 9) + lane * 8;
#pragma unroll
    for (int ks = 0; ks < 4; ks++)
        dstB[ks].i4 = *(const int4*)(base + ((ks * 2) << 9));
}

// one chunk (2 i-slots): 32 MFMA across 4 tile-chains (R7 shape)
__device__ __forceinline__ void msg_chunk4(int c, const F16x8* __restrict__ B,
                                           const unsigned short* const* hp,
                                           const f16x2 (*e2p)[4][4], f32x16* C) {
    unsigned int rr[4];
#pragma unroll
    for (int tt = 0; tt < 4; tt++) rr[tt] = *(const unsigned int*)(hp[tt] + 2 * c);
#pragma unroll
    for (int di = 0; di < 2; di++) {
        unsigned int sel = di ? 0x03020302u : 0x01000100u;
        F16x2U hh[4];
#pragma unroll
        for (int tt = 0; tt < 4; tt++) hh[tt].u = __builtin_amdgcn_perm(rr[tt], rr[tt], sel);
#pragma unroll
        for (int ks = 0; ks < 4; ks++) {
#pragma unroll
            for (int tt = 0; tt < 4; tt++) {
                F16x8 A;
#pragma unroll
                for (int r = 0; r < 4; r++) A.p[r] = hh[tt].h2 * e2p[tt][ks][r];
                C[tt] = __builtin_amdgcn_mfma_f32_32x32x16_f16(A.v, B[di * 4 + ks].v, C[tt], 0, 0, 0);
            }
        }
    }
}

// ================================================================ msg body: 256 edges, 4 waves,
// wave (eh,oq) = 4 edge-tiles x 32 outputs. Edge-MLP fully in registers, with
// stage-1/stage-2 INTERLEAVED PER TILE to cap the live register set
// (round-13 lesson: A1[4][4]+W2f+b2v+e2p all live at once -> 256-cap spill).
__device__ __forceinline__ void msg_body(MsgSmem& S, const float* __restrict__ h,
        const float* __restrict__ ea,
        const float* __restrict__ w1, const float* __restrict__ b1,
        const float* __restrict__ w2, const float* __restrict__ b2,
        const f16* __restrict__ Bpl,
        const int* __restrict__ srcp, const int* __restrict__ dstp,
        float* __restrict__ agg_l, int eb, int t) {
    const int lane = t & 63;
    const int w    = t >> 6;
    const int eh   = w >> 1, oq = w & 1;
    const int m    = lane & 31;
    const int kp   = lane >> 5;

    // ---- stage all 256 h rows (gathered by src, fp32 -> f16); dst
    {
        int nsrc = srcp[eb + t];
        const float4* hr = (const float4*)(h + (size_t)nsrc * 64);
        unsigned int* hrow = (unsigned int*)S.hsL + t * (HS_STRIDE / 2);
#pragma unroll
        for (int q = 0; q < 16; q++) {
            float4 v = hr[q];
            F16x2U p0, p1;
            p0.raw = __builtin_amdgcn_cvt_pkrtz(v.x, v.y);
            p1.raw = __builtin_amdgcn_cvt_pkrtz(v.z, v.w);
            hrow[q * 2 + 0] = p0.u;
            hrow[q * 2 + 1] = p1.u;
        }
        S.dstL[t] = dstp[eb + t];
    }

    // ---- stage-2 A-operand: w2 fragments (both output halves); b2 by C-row
    F16x8 W2f[2][4];
#pragma unroll
    for (int Hh = 0; Hh < 2; Hh++)
#pragma unroll
        for (int ks = 0; ks < 4; ks++) {
            const float* s = w2 + (size_t)(Hh * 32 + m) * 64 + ks * 16 + kp * 8;
            float4 a = ((const float4*)s)[0];
            float4 b = ((const float4*)s)[1];
            W2f[Hh][ks].p[0] = pkrtz(a.x, a.y);
            W2f[Hh][ks].p[1] = pkrtz(a.z, a.w);
            W2f[Hh][ks].p[2] = pkrtz(b.x, b.y);
            W2f[Hh][ks].p[3] = pkrtz(b.z, b.w);
        }
    float b2v[2][16];
#pragma unroll
    for (int Hh = 0; Hh < 2; Hh++)
#pragma unroll
        for (int reg = 0; reg < 16; reg++)
            b2v[Hh][reg] = b2[32 * Hh + (reg & 3) + 8 * (reg >> 2) + 4 * kp];

    // ---- edge-MLP per tile: e1 frags (regs) -> e2^T MFMA -> e2p[tt]
    f16x2 e2p[4][4][4];
#pragma unroll
    for (int tt = 0; tt < 4; tt++) {
        // stage 1: this tile's edge for this lane
        float ar[5];
        {
            int edge = eb + (eh * 4 + tt) * 32 + m;
#pragma unroll
            for (int d = 0; d < 5; d++) ar[d] = ea[(size_t)edge * 5 + d];
        }
        F16x8 A1[4];
#pragma unroll
        for (int ks = 0; ks < 4; ks++)
#pragma unroll
            for (int jj = 0; jj < 4; jj++) {
                int k0 = ks * 16 + kp * 8 + jj * 2;
                const float* wr0 = w1 + (size_t)k0 * 5;
                const float* wr1 = wr0 + 5;
                float v0 = b1[k0]     + ar[0] * wr0[0] + ar[1] * wr0[1] + ar[2] * wr0[2]
                                      + ar[3] * wr0[3] + ar[4] * wr0[4];
                float v1 = b1[k0 + 1] + ar[0] * wr1[0] + ar[1] * wr1[1] + ar[2] * wr1[2]
                                      + ar[3] * wr1[3] + ar[4] * wr1[4];
                A1[ks].p[jj] = pkrtz(leaky(v0), leaky(v1));
            }
        // stage 2: e2^T = w2 @ e1 (col = lane = edge)
        f32x16 C2a = {0,0,0,0,0,0,0,0,0,0,0,0,0,0,0,0};
        f32x16 C2b = {0,0,0,0,0,0,0,0,0,0,0,0,0,0,0,0};
#pragma unroll
        for (int ks = 0; ks < 4; ks++) {
            C2a = __builtin_amdgcn_mfma_f32_32x32x16_f16(W2f[0][ks].v, A1[ks].v, C2a, 0, 0, 0);
            C2b = __builtin_amdgcn_mfma_f32_32x32x16_f16(W2f[1][ks].v, A1[ks].v, C2b, 0, 0, 0);
        }
        // repack C-regs into pi-ordered A-fragments (all indices constant-folded)
#pragma unroll
        for (int jj = 0; jj < 4; jj++) {
            e2p[tt][0][jj] = pkrtz(leaky(C2a[2 * jj]     + b2v[0][2 * jj]),
                                   leaky(C2a[2 * jj + 1] + b2v[0][2 * jj + 1]));
            e2p[tt][1][jj] = pkrtz(leaky(C2a[8 + 2 * jj]     + b2v[0][8 + 2 * jj]),
                                   leaky(C2a[8 + 2 * jj + 1] + b2v[0][8 + 2 * jj + 1]));
            e2p[tt][2][jj] = pkrtz(leaky(C2b[2 * jj]     + b2v[1][2 * jj]),
                                   leaky(C2b[2 * jj + 1] + b2v[1][2 * jj + 1]));
            e2p[tt][3][jj] = pkrtz(leaky(C2b[8 + 2 * jj]     + b2v[1][8 + 2 * jj]),
                                   leaky(C2b[8 + 2 * jj + 1] + b2v[1][8 + 2 * jj + 1]));
        }
    }
    __syncthreads();   // hsL/dstL visibility (single barrier in msg)

    // ---- K-loop (R7 shape): 4 chains, static register dbuf, barrier-free
    f32x16 C[4];
#pragma unroll
    for (int tt = 0; tt < 4; tt++)
#pragma unroll
        for (int r = 0; r < 16; r++) C[tt][r] = 0.f;

    const unsigned short* hp[4];
#pragma unroll
    for (int tt = 0; tt < 4; tt++)
        hp[tt] = S.hsL + ((eh * 4 + tt) * 32 + m) * HS_STRIDE;

    F16x8 B0[8], B1[8];
    loadB8(Bpl, 0, oq, lane, B0);
    loadB8(Bpl, 1, oq, lane, B1);
    for (int it = 0; it < 15; it++) {
        int c = it * 2;
        msg_chunk4(c,     B0, hp, e2p, C);  loadB8(Bpl, c + 2, oq, lane, B0);
        msg_chunk4(c + 1, B1, hp, e2p, C);  loadB8(Bpl, c + 3, oq, lane, B1);
    }
    msg_chunk4(30, B0, hp, e2p, C);
    loadB4(Bpl, oq, lane, B0);              // bias frags
    msg_chunk4(31, B1, hp, e2p, C);

    // ---- bias chunk: A = h itself (linear k), B = eb3 frags
#pragma unroll
    for (int ks = 0; ks < 4; ks++) {
        int koff = (ks * 16 + kp * 8) * 2;
#pragma unroll
        for (int tt = 0; tt < 4; tt++) {
            const char* rp = (const char*)S.hsL + (size_t)((eh * 4 + tt) * 32 + m) * (HS_STRIDE * 2) + koff;
            F16x8 A;
            A.i2[0] = *(const int2*)(rp); A.i2[1] = *(const int2*)(rp + 8);
            C[tt] = __builtin_amdgcn_mfma_f32_32x32x16_f16(A.v, B0[ks].v, C[tt], 0, 0, 0);
        }
    }

    // ---- scatter epilogue
    int o = oq * 32 + m;
#pragma unroll
    for (int tt = 0; tt < 4; tt++) {
#pragma unroll
        for (int reg = 0; reg < 16; reg++) {
            int r = (reg & 3) + 8 * (reg >> 2) + 4 * kp;
            atomicAdd(&agg_l[(size_t)S.dstL[(eh * 4 + tt) * 32 + r] * 64 + o], C[tt][reg]);
        }
    }
}

// ================================================================ node / head bodies (proven)
__device__ __forceinline__ void node_body(NodeSmem& S, float* __restrict__ h,
        const float* __restrict__ agg_l, const float* __restrict__ deg,
        const float* __restrict__ rwl, const float* __restrict__ rbl,
        const float* __restrict__ lgl, const float* __restrict__ lbl,
        const int* __restrict__ bat, float* __restrict__ pooled,
        int last, int nb, int t) {
    const int lane = t & 63, w = t >> 6;
    const int nq = w >> 1, oq = w & 1;
    const int m = lane & 31, kp = lane >> 5;

    {
        int r = t >> 2, c0 = (t & 3) * 16;
        const float4* hr = (const float4*)(h + (size_t)(nb + r) * 64 + c0);
        unsigned int* drow = (unsigned int*)S.hA + r * 36 + c0 / 2;
#pragma unroll
        for (int q = 0; q < 4; q++) {
            float4 v = hr[q];
            F16x2U p0, p1;
            p0.raw = __builtin_amdgcn_cvt_pkrtz(v.x, v.y);
            p1.raw = __builtin_amdgcn_cvt_pkrtz(v.z, v.w);
            drow[q * 2] = p0.u; drow[q * 2 + 1] = p1.u;
        }
    }
    F16x8 Bf[4];
#pragma unroll
    for (int ks = 0; ks < 4; ks++) {
        const float* s = rwl + (size_t)(oq * 32 + m) * 64 + ks * 16 + kp * 8;
        float4 a = ((const float4*)s)[0];
        float4 b = ((const float4*)s)[1];
        Bf[ks].p[0] = pkrtz(a.x, a.y);
        Bf[ks].p[1] = pkrtz(a.z, a.w);
        Bf[ks].p[2] = pkrtz(b.x, b.y);
        Bf[ks].p[3] = pkrtz(b.z, b.w);
    }
    __syncthreads();

    f32x16 C = {0,0,0,0,0,0,0,0,0,0,0,0,0,0,0,0};
#pragma unroll
    for (int ks = 0; ks < 4; ks++) {
        F16x8 A;
        A.i4 = *(const int4*)(S.hA + (size_t)(nq * 32 + m) * 72 + ks * 16 + kp * 8);
        C = __builtin_amdgcn_mfma_f32_32x32x16_f16(A.v, Bf[ks].v, C, 0, 0, 0);
    }

    int o = oq * 32 + m;
#pragma unroll
    for (int reg = 0; reg < 16; reg++) {
        int r = (reg & 3) + 8 * (reg >> 2) + 4 * kp;
        int n = nq * 32 + r;
        S.outL[n][o] = C[reg] + rbl[o] + agg_l[(size_t)(nb + n) * 64 + o] / fmaxf(deg[nb + n], 1.0f);
    }
    __syncthreads();

    float gj = lgl[lane], bj = lbl[lane];
    float accp = 0.f;
    int cur = bat[nb + w * 16];
    for (int q = 0; q < 16; q++) {
        int n = w * 16 + q;
        float v = S.outL[n][lane];
        float mu = v;
#pragma unroll
        for (int msk = 32; msk > 0; msk >>= 1) mu += __shfl_xor(mu, msk);
        mu *= (1.f / 64.f);
        float d = v - mu;
        float var = d * d;
#pragma unroll
        for (int msk = 32; msk > 0; msk >>= 1) var += __shfl_xor(var, msk);
        var *= (1.f / 64.f);
        float ov = d * rsqrtf(var + LN_EPS) * gj + bj;
        float hn = leaky(ov) + h[(size_t)(nb + n) * 64 + lane];
        h[(size_t)(nb + n) * 64 + lane] = hn;
        if (last) {
            int b = bat[nb + n];
            if (b != cur) { atomicAdd(&pooled[cur * 64 + lane], accp); accp = 0.f; cur = b; }
            accp += hn;
        }
    }
    if (last) atomicAdd(&pooled[cur * 64 + lane], accp);
}

__device__ __forceinline__ void head_body(HeadSmem& S, const float* __restrict__ pooled,
        const int* __restrict__ bat,
        const float* pw1, const float* pb1, const float* pw2, const float* pb2,
        const float* pw3, const float* pb3, float* __restrict__ out, int t) {
    if (t < 32) S.cntL[t] = 0.f;
    __syncthreads();
    {
        const int4* bp4 = (const int4*)(bat + t * 64);
        int cur = bat[t * 64];
        float c = 0.f;
        for (int q = 0; q < 16; q++) {
            int4 b4 = bp4[q];
            int bs[4] = { b4.x, b4.y, b4.z, b4.w };
#pragma unroll
            for (int e = 0; e < 4; e++) {
                if (bs[e] != cur) { atomicAdd(&S.cntL[cur], c); cur = bs[e]; c = 0.f; }
                c += 1.f;
            }
        }
        atomicAdd(&S.cntL[cur], c);
    }
    __syncthreads();
    for (int idx = t; idx < 2048; idx += 256) {
        int b = idx >> 6, j = idx & 63;
        S.ps[b][j] = pooled[idx] / fmaxf(S.cntL[b], 1.0f);
    }
    __syncthreads();
    for (int idx = t; idx < 2048; idx += 256) {
        int b = idx >> 6, j = idx & 63;
        float v = pb1[j];
#pragma unroll 8
        for (int i = 0; i < 64; i++) v += S.ps[b][i] * pw1[j * 64 + i];
        S.p1[b][j] = leaky(v);
    }
    __syncthreads();
    for (int idx = t; idx < 1024; idx += 256) {
        int b = idx >> 5, j = idx & 31;
        float v = pb2[j];
#pragma unroll 8
        for (int i = 0; i < 64; i++) v += S.p1[b][i] * pw2[j * 64 + i];
        S.p2[b][j] = leaky(v);
    }
    __syncthreads();
    if (t < 32) {
        float v = pb3[0];
#pragma unroll 8
        for (int i = 0; i < 32; i++) v += S.p2[t][i] * pw3[i];
        out[t] = v;
    }
}

// ================================================================ cooperative mega-kernel (grid 256)
__global__ __launch_bounds__(256, 1) void k_all(Params P) {
    __shared__ AllSmem smem;
    cg::grid_group grid = cg::this_grid();

    const int t   = threadIdx.x;
    const int bid = blockIdx.x;
    const int w   = t >> 6;

    float* ws     = P.ws;
    float* h      = ws;
    float* agg    = ws + 1048576;
    float* deg    = ws + 4194304;
    float* pooled = ws + 4210688;
    f16*   Bp     = (f16*)(ws + 4212800);
    const int* srcp = P.eidx;
    const int* dstp = P.eidx + N_EDGES;

    // phase S: inproj + degree + Bp prep (zeroing done by host memset)
    {
        int base = bid * 4096;
#pragma unroll
        for (int q = 0; q < 16; q++) {
            int idx = base + q * 256 + t;
            int n = idx >> 6, j = idx & 63;
            const float* xr = P.x + n * 4;
            const float* wr = P.Win + j * 4;
            float v = P.bin[j] + xr[0] * wr[0] + xr[1] * wr[1] + xr[2] * wr[2] + xr[3] * wr[3];
            h[idx] = leaky(v);
        }
        atomicAdd(&deg[dstp[bid * 256 + t]], 1.0f);
        for (int gslot = bid * 4 + w; gslot < 1560; gslot += 1024)
            bp_slot(gslot, t & 63, P.ew3, P.eb3, Bp);
    }
    grid.sync();

#pragma unroll 1
    for (int l = 0; l < NLAYERS; l++) {
        float* agg_l = agg + (size_t)l * 1048576;
        msg_body(smem.m, h, P.ea, P.ew1 + l * 320, P.eb1 + l * 64,
                 P.ew2 + l * 4096, P.eb2 + l * 64,
                 Bp + (size_t)l * 266240, srcp, dstp, agg_l, bid * 256, t);
        grid.sync();
        node_body(smem.n, h, agg_l, deg, P.rw + l * 4096, P.rb + l * 64,
                  P.lg + l * 64, P.lb + l * 64, P.bat, pooled,
                  (l == NLAYERS - 1) ? 1 : 0, bid * 64, t);
        grid.sync();
    }

    if (bid == 0)
        head_body(smem.hd, pooled, P.bat, P.pw1, P.pb1, P.pw2, P.pb2, P.pw3, P.pb3, P.out, t);
}

// ================================================================ fallback kernels (multi-dispatch)
__global__ __launch_bounds__(256) void k_setup(const float* __restrict__ x,
                                               const float* __restrict__ Win,
                                               const float* __restrict__ bin,
                                               const int* __restrict__ dst,
                                               const float* __restrict__ ew3,
                                               const float* __restrict__ eb3,
                                               float* __restrict__ h,
                                               float* __restrict__ deg,
                                               f16* __restrict__ Bp) {
    int bid = blockIdx.x;
    if (bid < 4096) {
        int t = bid * 256 + threadIdx.x;
        int n = t >> 6, j = t & 63;
        const float* xr = x + n * 4;
        const float* wr = Win + j * 4;
        float v = bin[j] + xr[0] * wr[0] + xr[1] * wr[1] + xr[2] * wr[2] + xr[3] * wr[3];
        h[t] = leaky(v);
    } else if (bid < 4352) {
        int e = (bid - 4096) * 256 + threadIdx.x;
        atomicAdd(&deg[dst[e]], 1.0f);
    } else {
        int tg = (bid - 4352) * 256 + threadIdx.x;
        bp_slot(tg >> 6, tg & 63, ew3, eb3, Bp);
    }
}

__global__ __launch_bounds__(256, 1) void k_msg_s(const float* __restrict__ h,
                                                  const float* __restrict__ ea,
                                                  const float* __restrict__ w1,
                                                  const float* __restrict__ b1,
                                                  const float* __restrict__ w2,
                                                  const float* __restrict__ b2,
                                                  const f16* __restrict__ Bp,
                                                  const int* __restrict__ src,
                                                  const int* __restrict__ dst,
                                                  float* __restrict__ agg) {
    __shared__ MsgSmem S;
    msg_body(S, h, ea, w1, b1, w2, b2, Bp, src, dst, agg, blockIdx.x * 256, threadIdx.x);
}

__global__ __launch_bounds__(256) void k_node_s(const float* __restrict__ agg,
                                                const float* __restrict__ deg,
                                                const float* __restrict__ rw,
                                                const float* __restrict__ rb,
                                                const float* __restrict__ lg,
                                                const float* __restrict__ lb,
                                                float* __restrict__ h,
                                                const int* __restrict__ batch,
                                                float* __restrict__ pooled,
                                                int last) {
    __shared__ NodeSmem S;
    node_body(S, h, agg, deg, rw, rb, lg, lb, batch, pooled, last, blockIdx.x * 64, threadIdx.x);
}

__global__ __launch_bounds__(256) void k_head_s(const float* __restrict__ pooled,
                                                const int* __restrict__ batch,
                                                const float* __restrict__ pw1, const float* __restrict__ pb1,
                                                const float* __restrict__ pw2, const float* __restrict__ pb2,
                                                const float* __restrict__ pw3, const float* __restrict__ pb3,
                                                float* __restrict__ out) {
    __shared__ HeadSmem S;
    head_body(S, pooled, batch, pw1, pb1, pw2, pb2, pw3, pb3, out, threadIdx.x);
}

// ----------------------------------------------------------------
extern "C" void kernel_launch(void* const* d_in, const int* in_sizes, int n_in,
                              void* d_out, int out_size, void* d_ws, size_t ws_size,
                              hipStream_t stream) {
    Params hp;
    hp.x    = (const float*)d_in[0];
    hp.eidx = (const int*)  d_in[1];
    hp.ea   = (const float*)d_in[2];
    hp.bat  = (const int*)  d_in[3];
    hp.Win  = (const float*)d_in[4];
    hp.bin  = (const float*)d_in[5];
    hp.ew1  = (const float*)d_in[6];
    hp.eb1  = (const float*)d_in[7];
    hp.ew2  = (const float*)d_in[8];
    hp.eb2  = (const float*)d_in[9];
    hp.ew3  = (const float*)d_in[10];
    hp.eb3  = (const float*)d_in[11];
    hp.rw   = (const float*)d_in[12];
    hp.rb   = (const float*)d_in[13];
    hp.lg   = (const float*)d_in[14];
    hp.lb   = (const float*)d_in[15];
    hp.pw1  = (const float*)d_in[16];
    hp.pb1  = (const float*)d_in[17];
    hp.pw2  = (const float*)d_in[18];
    hp.pb2  = (const float*)d_in[19];
    hp.pw3  = (const float*)d_in[20];
    hp.pb3  = (const float*)d_in[21];
    hp.out  = (float*)d_out;
    hp.ws   = (float*)d_ws;

    float* ws  = (float*)d_ws;
    float* agg = ws + 1048576;
    (void)hipMemsetAsync(agg, 0, (size_t)3164224 * sizeof(float), stream);

    void* args[] = { (void*)&hp };
    hipError_t err = hipLaunchCooperativeKernel(reinterpret_cast<void*>(k_all),
                                                dim3(256), dim3(256), args, 0, stream);
    if (err != hipSuccess) {
        float* h      = ws;
        float* deg    = ws + 4194304;
        float* pooled = ws + 4210688;
        f16*   Bp     = (f16*)(ws + 4212800);
        const int* srcp = (const int*)d_in[1];
        const int* dstp = srcp + N_EDGES;

        k_setup<<<4742, 256, 0, stream>>>(hp.x, hp.Win, hp.bin, dstp, hp.ew3, hp.eb3, h, deg, Bp);
        for (int l = 0; l < NLAYERS; l++) {
            float* agg_l = agg + (size_t)l * 1048576;
            k_msg_s <<<N_EDGES / 256, 256, 0, stream>>>(h, hp.ea, hp.ew1 + l * 320, hp.eb1 + l * 64,
                                                        hp.ew2 + l * 4096, hp.eb2 + l * 64,
                                                        Bp + (size_t)l * 266240, srcp, dstp, agg_l);
            k_node_s<<<N_NODES / 64, 256, 0, stream>>>(agg_l, deg, hp.rw + l * 4096, hp.rb + l * 64,
                                                       hp.lg + l * 64, hp.lb + l * 64, h,
                                                       hp.bat, pooled, l == NLAYERS - 1 ? 1 : 0);
        }
        k_head_s<<<1, 256, 0, stream>>>(pooled, hp.bat, hp.pw1, hp.pb1, hp.pw2, hp.pb2,
                                        hp.pw3, hp.pb3, (float*)d_out);
    }
}